// Round 11
// baseline (1389.865 us; speedup 1.0000x reference)
//
#include <hip/hip_runtime.h>
#include <stdint.h>
#include <math.h>

// ---------------------------------------------------------------------------
// NanochatMiniLM forward on MI355X. Round 11: LM head ported to a 256x256
// BK=64 8-wave counted-vmcnt pipeline (T3+T4): per K-tile two phases
// {stage region-pair; vmcnt(8); s_barrier; ds_read; 32 MFMA; s_barrier} --
// vmcnt never drains in the loop (1 K-tile always in flight). LDS layout
// [2 kslice][256 row][32 kcol] makes gload_lds dests linear AND ds_read_b128
// bank-floor-uniform (no swizzle needed). Raw s_barrier only (no
// __syncthreads => no forced vmcnt(0)); sched_barrier(0) pins motion.
// WAR/vmcnt FIFO ledger documented inline. Other GEMMs keep R10 structure.
// B=2 T=1024 D=1024 H=16 KV=4 HD=64 L=6 VP=32000, windows {256,1024,...}
// ---------------------------------------------------------------------------

using bf16x8 = __attribute__((ext_vector_type(8))) short;   // 8 bf16 (4 VGPRs)
using f32x4  = __attribute__((ext_vector_type(4))) float;   // 4 f32 acc

#define DEV static __device__ __forceinline__

DEV unsigned short f2bf(float f) {            // RNE f32 -> bf16 bits
  unsigned int x = __builtin_bit_cast(unsigned int, f);
  x += 0x7fffu + ((x >> 16) & 1u);
  return (unsigned short)(x >> 16);
}
DEV float bf2f(unsigned short u) {
  return __builtin_bit_cast(float, (unsigned int)u << 16);
}
DEV unsigned int packbf2(float a, float b) {
  return (unsigned int)f2bf(a) | ((unsigned int)f2bf(b) << 16);
}

// async global->LDS, 16B per lane; LDS dest is wave-uniform base + lane*16
DEV void gload16(const unsigned short* g, unsigned short* l) {
  __builtin_amdgcn_global_load_lds(
      (__attribute__((address_space(1))) void*)const_cast<unsigned short*>(g),
      (__attribute__((address_space(3))) void*)l, 16, 0, 0);
}

// ------------------- merged weight conversion (one launch) -----------------

extern "C" __global__ __launch_bounds__(256)
void prep_weights_kernel(const float* __restrict__ Wq, const float* __restrict__ Wk,
                         const float* __restrict__ Wv, const float* __restrict__ Wo,
                         const float* __restrict__ Wfc, const float* __restrict__ Wmp,
                         const float* __restrict__ LmW,
                         unsigned short* __restrict__ wqkv, unsigned short* __restrict__ wo,
                         unsigned short* __restrict__ wfc, unsigned short* __restrict__ wmp,
                         unsigned short* __restrict__ wlm) {
  const long v = (long)blockIdx.x * 256 + threadIdx.x;   // vector index
  const long S0 = 1179648, S1 = S0 + 786432, S2 = S1 + 3145728,
             S3 = S2 + 3145728, S4 = S3 + 4096000;
  const float* src; unsigned short* dst;
  if (v < S0) {
    const long i = v * 8;
    const int c = (int)(i & 1023);
    const int row = (int)(i >> 10);
    const int l = row / 1536, r = row - l * 1536;
    if (r < 1024)      src = Wq + ((size_t)l * 1024 + r) * 1024 + c;
    else if (r < 1280) src = Wk + ((size_t)l * 256 + (r - 1024)) * 1024 + c;
    else               src = Wv + ((size_t)l * 256 + (r - 1280)) * 1024 + c;
    dst = wqkv + i;
  } else if (v < S1) {
    const long i = (v - S0) * 8; src = Wo + i;  dst = wo + i;
  } else if (v < S2) {
    const long i = (v - S1) * 8; src = Wfc + i; dst = wfc + i;
  } else if (v < S3) {
    const long i = (v - S2) * 8; src = Wmp + i; dst = wmp + i;
  } else if (v < S4) {
    const long i = (v - S3) * 8; src = LmW + i; dst = wlm + i;
  } else {
    return;
  }
  const float4 a = *reinterpret_cast<const float4*>(src);
  const float4 b = *reinterpret_cast<const float4*>(src + 4);
  uint4 u;
  u.x = packbf2(a.x, a.y); u.y = packbf2(a.z, a.w);
  u.z = packbf2(b.x, b.y); u.w = packbf2(b.z, b.w);
  *reinterpret_cast<uint4*>(dst) = u;
}

// ------------------------------- rope tables -------------------------------

extern "C" __global__ __launch_bounds__(256)
void rope_tab_kernel(float* __restrict__ cost, float* __restrict__ sint) {
  const int idx = blockIdx.x * 256 + threadIdx.x;   // t*32 + i, 32768 total
  const int t = idx >> 5, i = idx & 31;
  const double inv = exp(((double)i * (-1.0 / 32.0)) * log(100000.0));
  const double f = (double)t * inv;
  cost[idx] = (float)cos(f);
  sint[idx] = (float)sin(f);
}

// ------------- embedding + rms + smear + fused l=0 combine+rms -------------

extern "C" __global__ __launch_bounds__(256)
void embed_kernel(const int* __restrict__ ids, const float* __restrict__ wte,
                  const float* __restrict__ smear_w, const float* __restrict__ smear_l,
                  const float* __restrict__ residc, const float* __restrict__ x0c,
                  float* __restrict__ x, float* __restrict__ x0,
                  unsigned short* __restrict__ xn) {
  const int wid = threadIdx.x >> 6, lane = threadIdx.x & 63;
  const int tok = blockIdx.x * 4 + wid;
  const int t = tok & 1023;
  const float eps = 1.1920929e-7f;

  const float* wrow = wte + (size_t)ids[tok] * 1024;
  float4 v[4];
  float ss = 0.f;
#pragma unroll
  for (int i = 0; i < 4; ++i) {
    v[i] = *reinterpret_cast<const float4*>(wrow + i * 256 + lane * 4);
    ss += v[i].x * v[i].x + v[i].y * v[i].y + v[i].z * v[i].z + v[i].w * v[i].w;
  }
#pragma unroll
  for (int m = 1; m < 64; m <<= 1) ss += __shfl_xor(ss, m);
  const float sc = 1.f / sqrtf(ss * (1.f / 1024.f) + eps);

  float4 pv[4];
#pragma unroll
  for (int i = 0; i < 4; ++i) { pv[i].x = 0.f; pv[i].y = 0.f; pv[i].z = 0.f; pv[i].w = 0.f; }
  float scp = 0.f, gate = 0.f;
  if (t > 0) {
    const float* prow = wte + (size_t)ids[tok - 1] * 1024;
    float ssp = 0.f;
#pragma unroll
    for (int i = 0; i < 4; ++i) {
      pv[i] = *reinterpret_cast<const float4*>(prow + i * 256 + lane * 4);
      ssp += pv[i].x * pv[i].x + pv[i].y * pv[i].y + pv[i].z * pv[i].z + pv[i].w * pv[i].w;
    }
#pragma unroll
    for (int m = 1; m < 64; m <<= 1) ssp += __shfl_xor(ssp, m);
    scp = 1.f / sqrtf(ssp * (1.f / 1024.f) + eps);
    float gp = 0.f;
    if (lane < 6) {
      gp = v[0].x * smear_w[lane * 4] + v[0].y * smear_w[lane * 4 + 1] +
           v[0].z * smear_w[lane * 4 + 2] + v[0].w * smear_w[lane * 4 + 3];
      gp *= sc;
    }
#pragma unroll
    for (int m = 1; m < 64; m <<= 1) gp += __shfl_xor(gp, m);
    gate = smear_l[0] / (1.f + __expf(-gp));
  }
  const float a0 = residc[0], b0 = x0c[0];
  float4 y[4];
  float ssy = 0.f;
#pragma unroll
  for (int i = 0; i < 4; ++i) {
    const int c = i * 256 + lane * 4;
    float4 o;
    o.x = v[i].x * sc + gate * pv[i].x * scp;
    o.y = v[i].y * sc + gate * pv[i].y * scp;
    o.z = v[i].z * sc + gate * pv[i].z * scp;
    o.w = v[i].w * sc + gate * pv[i].w * scp;
    *reinterpret_cast<float4*>(x0 + (size_t)tok * 1024 + c) = o;
    float4 yy;
    yy.x = a0 * o.x + b0 * o.x; yy.y = a0 * o.y + b0 * o.y;
    yy.z = a0 * o.z + b0 * o.z; yy.w = a0 * o.w + b0 * o.w;
    *reinterpret_cast<float4*>(x + (size_t)tok * 1024 + c) = yy;
    y[i] = yy;
    ssy += yy.x * yy.x + yy.y * yy.y + yy.z * yy.z + yy.w * yy.w;
  }
#pragma unroll
  for (int m = 1; m < 64; m <<= 1) ssy += __shfl_xor(ssy, m);
  const float scy = 1.f / sqrtf(ssy * (1.f / 1024.f) + eps);
#pragma unroll
  for (int i = 0; i < 4; ++i) {
    const int c = i * 256 + lane * 4;
    ushort4 u;
    u.x = f2bf(y[i].x * scy); u.y = f2bf(y[i].y * scy);
    u.z = f2bf(y[i].z * scy); u.w = f2bf(y[i].w * scy);
    *reinterpret_cast<ushort4*>(xn + (size_t)tok * 1024 + c) = u;
  }
}

// ------------- residual mix + split-K partial reduce + rmsnorm -------------

extern "C" __global__ __launch_bounds__(256)
void rmsnorm_kernel(float* __restrict__ x, const float* __restrict__ x0,
                    const float* __restrict__ parts, int np,
                    const float* __restrict__ residc, const float* __restrict__ x0c,
                    int layer, int combine, unsigned short* __restrict__ xn) {
  const int wid = threadIdx.x >> 6, lane = threadIdx.x & 63;
  const int tok = blockIdx.x * 4 + wid;
  float* xr = x + (size_t)tok * 1024;
  const float* x0r = x0 + (size_t)tok * 1024;
  float a = 1.f, bb = 0.f;
  if (combine) { a = residc[layer]; bb = x0c[layer]; }
  float4 v[4];
  float ss = 0.f;
#pragma unroll
  for (int i = 0; i < 4; ++i) {
    const int c = i * 256 + lane * 4;
    float4 xv = *reinterpret_cast<const float4*>(xr + c);
    for (int pi = 0; pi < np; ++pi) {
      const float4 pv = *reinterpret_cast<const float4*>(
          parts + (size_t)pi * 2048 * 1024 + (size_t)tok * 1024 + c);
      xv.x += pv.x; xv.y += pv.y; xv.z += pv.z; xv.w += pv.w;
    }
    if (combine) {
      const float4 ov = *reinterpret_cast<const float4*>(x0r + c);
      xv.x = a * xv.x + bb * ov.x; xv.y = a * xv.y + bb * ov.y;
      xv.z = a * xv.z + bb * ov.z; xv.w = a * xv.w + bb * ov.w;
    }
    if (combine || np > 0) *reinterpret_cast<float4*>(xr + c) = xv;
    v[i] = xv;
    ss += xv.x * xv.x + xv.y * xv.y + xv.z * xv.z + xv.w * xv.w;
  }
#pragma unroll
  for (int m = 1; m < 64; m <<= 1) ss += __shfl_xor(ss, m);
  const float sc = 1.f / sqrtf(ss * (1.f / 1024.f) + 1.1920929e-7f);
#pragma unroll
  for (int i = 0; i < 4; ++i) {
    const int c = i * 256 + lane * 4;
    ushort4 u;
    u.x = f2bf(v[i].x * sc); u.y = f2bf(v[i].y * sc);
    u.z = f2bf(v[i].z * sc); u.w = f2bf(v[i].w * sc);
    *reinterpret_cast<ushort4*>(xn + (size_t)tok * 1024 + c) = u;
  }
}

// ------------------- qkv post: rope + rms + ve-gate -> bf16 ----------------

extern "C" __global__ __launch_bounds__(256)
void qkv_post_kernel(const float* __restrict__ qkv0, const float* __restrict__ qkv1,
                     const unsigned short* __restrict__ xn,
                     const int* __restrict__ ids,
                     const float* __restrict__ ve_tab, const float* __restrict__ ve_gate_w,
                     const float* __restrict__ cost, const float* __restrict__ sint,
                     unsigned short* __restrict__ qb, unsigned short* __restrict__ kbuf,
                     unsigned short* __restrict__ vb) {
  const int wid = threadIdx.x >> 6, lane = threadIdx.x & 63;
  const int tok = blockIdx.x * 4 + wid;
  const int t = tok & 1023;
  const float eps = 1.1920929e-7f;
  const float* rowA = qkv0 + (size_t)tok * 1536;
  const float* rowB = qkv1 + (size_t)tok * 1536;
  const bool x1half = (lane & 2) == 0;   // lane%4 in {0,1}: x1; {2,3}: x2
  const int i0 = (lane & 1) << 4;        // rotary index base within half

  // ---- Q: 16 heads * 64, scale = 1.2/8 folded in ----
  {
    float v[16], p[16];
    {
      const float4* ra = reinterpret_cast<const float4*>(rowA + lane * 16);
      const float4* rb = reinterpret_cast<const float4*>(rowB + lane * 16);
#pragma unroll
      for (int i = 0; i < 4; ++i) {
        const float4 qa = ra[i], qb4 = rb[i];
        v[i * 4] = qa.x + qb4.x; v[i * 4 + 1] = qa.y + qb4.y;
        v[i * 4 + 2] = qa.z + qb4.z; v[i * 4 + 3] = qa.w + qb4.w;
      }
    }
#pragma unroll
    for (int i = 0; i < 16; ++i) p[i] = __shfl_xor(v[i], 2);
    float out[16]; float ssq = 0.f;
#pragma unroll
    for (int i = 0; i < 16; ++i) {
      const float c = cost[t * 32 + i0 + i];
      const float s = sint[t * 32 + i0 + i];
      out[i] = x1half ? (v[i] * c + p[i] * s) : (v[i] * c - p[i] * s);
      ssq += out[i] * out[i];
    }
    ssq += __shfl_xor(ssq, 1);
    ssq += __shfl_xor(ssq, 2);
    const float sc = 0.15f / sqrtf(ssq * (1.f / 64.f) + eps);
#pragma unroll
    for (int i = 0; i < 16; i += 4) {
      ushort4 u;
      u.x = f2bf(out[i] * sc); u.y = f2bf(out[i + 1] * sc);
      u.z = f2bf(out[i + 2] * sc); u.w = f2bf(out[i + 3] * sc);
      *reinterpret_cast<ushort4*>(qb + (size_t)tok * 1024 + lane * 16 + i) = u;
    }
  }
  const int kl = lane & 15;  // lanes 16-63 mirror 0-15 (keeps shfl uniform)
  // ---- K: 4 kv heads * 64, scale 1.2 ----
  {
    float v[16], p[16];
    {
      const float4* ra = reinterpret_cast<const float4*>(rowA + 1024 + kl * 16);
      const float4* rb = reinterpret_cast<const float4*>(rowB + 1024 + kl * 16);
#pragma unroll
      for (int i = 0; i < 4; ++i) {
        const float4 qa = ra[i], qb4 = rb[i];
        v[i * 4] = qa.x + qb4.x; v[i * 4 + 1] = qa.y + qb4.y;
        v[i * 4 + 2] = qa.z + qb4.z; v[i * 4 + 3] = qa.w + qb4.w;
      }
    }
#pragma unroll
    for (int i = 0; i < 16; ++i) p[i] = __shfl_xor(v[i], 2);
    float out[16]; float ssq = 0.f;
#pragma unroll
    for (int i = 0; i < 16; ++i) {
      const float c = cost[t * 32 + i0 + i];
      const float s = sint[t * 32 + i0 + i];
      out[i] = x1half ? (v[i] * c + p[i] * s) : (v[i] * c - p[i] * s);
      ssq += out[i] * out[i];
    }
    ssq += __shfl_xor(ssq, 1);
    ssq += __shfl_xor(ssq, 2);
    const float sc = 1.2f / sqrtf(ssq * (1.f / 64.f) + eps);
    if (lane < 16) {
#pragma unroll
      for (int i = 0; i < 16; i += 4) {
        ushort4 u;
        u.x = f2bf(out[i] * sc); u.y = f2bf(out[i + 1] * sc);
        u.z = f2bf(out[i + 2] * sc); u.w = f2bf(out[i + 3] * sc);
        *reinterpret_cast<ushort4*>(kbuf + (size_t)tok * 256 + kl * 16 + i) = u;
      }
    }
  }
  // ---- V: optional value-embedding gate ----
  {
    float v[16];
    {
      const float4* ra = reinterpret_cast<const float4*>(rowA + 1280 + kl * 16);
      const float4* rb = reinterpret_cast<const float4*>(rowB + 1280 + kl * 16);
#pragma unroll
      for (int i = 0; i < 4; ++i) {
        const float4 qa = ra[i], qb4 = rb[i];
        v[i * 4] = qa.x + qb4.x; v[i * 4 + 1] = qa.y + qb4.y;
        v[i * 4 + 2] = qa.z + qb4.z; v[i * 4 + 3] = qa.w + qb4.w;
      }
    }
    if (ve_tab != nullptr) {
      const int kvh = kl >> 2;
      float g = 0.f;
#pragma unroll
      for (int c = 0; c < 12; ++c)
        g += bf2f(xn[(size_t)tok * 1024 + c]) * ve_gate_w[kvh * 12 + c];
      g = 3.f / (1.f + __expf(-g));
      const float* ver = ve_tab + (size_t)ids[tok] * 256 + kl * 16;
#pragma unroll
      for (int i = 0; i < 16; ++i) v[i] += g * ver[i];
    }
    if (lane < 16) {
#pragma unroll
      for (int i = 0; i < 16; i += 4) {
        ushort4 u;
        u.x = f2bf(v[i]); u.y = f2bf(v[i + 1]); u.z = f2bf(v[i + 2]); u.w = f2bf(v[i + 3]);
        *reinterpret_cast<ushort4*>(vb + (size_t)tok * 256 + kl * 16 + i) = u;
      }
    }
  }
}

// ---------------- V transpose: vb[b][t][kv*64+d] -> vt[b*4+kv][d][t] -------

extern "C" __global__ __launch_bounds__(256)
void vtrans_kernel(const unsigned short* __restrict__ vb, unsigned short* __restrict__ vt) {
  __shared__ unsigned short tile[64][72];
  const int t0 = blockIdx.x << 6;
  const int bk = blockIdx.y;               // b*4 + kv
  const int tid = threadIdx.x;
  {
    const int r = tid >> 2, cs = (tid & 3) << 4;
    const unsigned short* src = vb + ((size_t)((bk >> 2) * 1024 + t0 + r)) * 256 + (bk & 3) * 64 + cs;
    *reinterpret_cast<uint4*>(&tile[r][cs]) = *reinterpret_cast<const uint4*>(src);
    *reinterpret_cast<uint4*>(&tile[r][cs + 8]) = *reinterpret_cast<const uint4*>(src + 8);
  }
  __syncthreads();
  {
    const int d = tid >> 2, ts = (tid & 3) << 4;
    unsigned int w[8];
#pragma unroll
    for (int i = 0; i < 8; ++i)
      w[i] = (unsigned int)tile[ts + 2 * i][d] | ((unsigned int)tile[ts + 2 * i + 1][d] << 16);
    unsigned short* dst = vt + ((size_t)bk * 64 + d) * 1024 + t0 + ts;
    uint4 u0; u0.x = w[0]; u0.y = w[1]; u0.z = w[2]; u0.w = w[3];
    uint4 u1; u1.x = w[4]; u1.y = w[5]; u1.z = w[6]; u1.w = w[7];
    *reinterpret_cast<uint4*>(dst) = u0;
    *reinterpret_cast<uint4*>(dst + 8) = u1;
  }
}

// --------------------------- flash attention -------------------------------

extern "C" __global__ __launch_bounds__(64)
void attn_kernel(const unsigned short* __restrict__ qb,
                 const unsigned short* __restrict__ kb,
                 const unsigned short* __restrict__ vt,
                 unsigned short* __restrict__ y, int W) {
  __shared__ unsigned short p_lds[16 * 32];
  const int lane = threadIdx.x;
  const int q0 = blockIdx.x << 4;
  const int h = blockIdx.y;
  const int b = blockIdx.z;
  const int kv = h >> 2;
  const int lr = lane & 15, lk = lane >> 4;

  bf16x8 qf0, qf1;
  {
    const unsigned short* qrow = qb + ((size_t)(b * 1024 + q0 + lr)) * 1024 + h * 64 + (lk << 3);
    qf0 = *reinterpret_cast<const bf16x8*>(qrow);
    qf1 = *reinterpret_cast<const bf16x8*>(qrow + 32);
  }
  f32x4 acc[4] = {};
  float m_run = -3e38f, l_run = 0.f;
  int kstart = q0 - W + 1; if (kstart < 0) kstart = 0;
  kstart &= ~31;
  const int qq = q0 + lr;

  for (int kb0 = kstart; kb0 < q0 + 16; kb0 += 32) {
    f32x4 st[2];
#pragma unroll
    for (int s = 0; s < 2; ++s) {
      const unsigned short* krow = kb + ((size_t)(b * 1024 + kb0 + (s << 4) + lr)) * 256 + kv * 64 + (lk << 3);
      bf16x8 kf0 = *reinterpret_cast<const bf16x8*>(krow);
      bf16x8 kf1 = *reinterpret_cast<const bf16x8*>(krow + 32);
      f32x4 z = {0.f, 0.f, 0.f, 0.f};
      z = __builtin_amdgcn_mfma_f32_16x16x32_bf16(kf0, qf0, z, 0, 0, 0);
      st[s] = __builtin_amdgcn_mfma_f32_16x16x32_bf16(kf1, qf1, z, 0, 0, 0);
    }
    float sv[8];
    float bm = -3e38f;
#pragma unroll
    for (int s = 0; s < 2; ++s)
#pragma unroll
      for (int j = 0; j < 4; ++j) {
        const int key = kb0 + (s << 4) + (lk << 2) + j;
        const bool valid = (key <= qq) && (qq - key < W);
        const float xx = valid ? st[s][j] : -3e38f;
        sv[s * 4 + j] = xx;
        bm = fmaxf(bm, xx);
      }
    bm = fmaxf(bm, __shfl_xor(bm, 16));
    bm = fmaxf(bm, __shfl_xor(bm, 32));
    const float m_new = fmaxf(m_run, bm);
    const float alpha = __expf(m_run - m_new);
    float psum = 0.f;
    unsigned short pbv[8];
#pragma unroll
    for (int s = 0; s < 2; ++s)
#pragma unroll
      for (int j = 0; j < 4; ++j) {
        const int key = kb0 + (s << 4) + (lk << 2) + j;
        const bool valid = (key <= qq) && (qq - key < W);
        const float pv = valid ? __expf(sv[s * 4 + j] - m_new) : 0.f;
        psum += pv;
        pbv[s * 4 + j] = f2bf(pv);
      }
    psum += __shfl_xor(psum, 16);
    psum += __shfl_xor(psum, 32);
    l_run = l_run * alpha + psum;
    m_run = m_new;

    __syncthreads();  // WAR vs previous iteration's reads
    {
      ushort4 u0, u1;
      u0.x = pbv[0]; u0.y = pbv[1]; u0.z = pbv[2]; u0.w = pbv[3];
      u1.x = pbv[4]; u1.y = pbv[5]; u1.z = pbv[6]; u1.w = pbv[7];
      *reinterpret_cast<ushort4*>(p_lds + lr * 32 + (lk << 2)) = u0;
      *reinterpret_cast<ushort4*>(p_lds + lr * 32 + 16 + (lk << 2)) = u1;
    }
    __syncthreads();
    const bf16x8 pf = *reinterpret_cast<const bf16x8*>(p_lds + lr * 32 + (lk << 3));
    float al[4];
#pragma unroll
    for (int j = 0; j < 4; ++j) al[j] = __shfl(alpha, (lk << 2) + j);
#pragma unroll
    for (int d = 0; d < 4; ++d) {
      const unsigned short* vrow = vt + ((size_t)((b * 4 + kv) * 64 + (d << 4) + lr)) * 1024 + kb0 + (lk << 3);
      const bf16x8 vf = *reinterpret_cast<const bf16x8*>(vrow);
#pragma unroll
      for (int j = 0; j < 4; ++j) acc[d][j] *= al[j];
      acc[d] = __builtin_amdgcn_mfma_f32_16x16x32_bf16(pf, vf, acc[d], 0, 0, 0);
    }
  }
  float linv[4];
#pragma unroll
  for (int j = 0; j < 4; ++j) linv[j] = 1.f / __shfl(l_run, (lk << 2) + j);
#pragma unroll
  for (int d = 0; d < 4; ++d)
#pragma unroll
    for (int j = 0; j < 4; ++j) {
      const int qrow = q0 + (lk << 2) + j;
      y[((size_t)(b * 1024 + qrow)) * 1024 + h * 64 + (d << 4) + lr] = f2bf(acc[d][j] * linv[j]);
    }
}

// ------------- gemm256: 256x256 / BK=64 / 8 waves, counted vmcnt -----------
// LDS per buffer: A[2 kslice][256 row][32 kcol] + B same (32 KB each op);
// double-buffered -> 128 KB. Region = (op, kslice) = 16 KB = 2 gload rounds;
// round: thread -> row h*128+(tid>>2), kcol (tid&3)*8; LDS dst = tid*16B
// within round (wave-uniform + lane*16 ✓). ds_read_b128 of a fragment:
// byte = r*64 + lk*16 -> bank floor-uniform (8 words/bank) = conflict-free.
//
// Schedule per K-tile t (buffer cb=t&1), 2 phases:
//  ph0 (kk=0): stage A-hi,B-hi of t+1 -> buf[(t+1)&1] (freed at t-1 ph1 bar)
//              vmcnt(8)  [FIFO: allows t+1's 4 regions; t's all landed]
//              s_barrier; sched_barrier; ds_read 12; 32 MFMA; s_barrier
//  ph1 (kk=1): stage A-lo,B-lo of t+2 -> buf[cb] lo (freed at ph0 bar)
//              vmcnt(8)  [allows t+1 lo+hi, t+2 lo... oldest pending -> t's
//              hi landed]; s_barrier; sched_barrier; reads; MFMA; s_barrier
// Prologue: t0{Alo,Blo,Ahi,Bhi}, t1{Alo,Blo} (12 loads). Tail stages clamp
// src tile (counts uniform; dead regions). vmcnt(0) after loop.
// Raw s_barrier only — no __syncthreads => no compiler vmcnt(0) drain.
// EPI==3: softcap f32 out. C^T operand-swap epilogue (quad spans N).

template <int EPI>
__global__ __launch_bounds__(512)
void gemm256(const unsigned short* __restrict__ A,
             const unsigned short* __restrict__ Bw,
             void* __restrict__ Cout, int M, int N, int K) {
  __shared__ unsigned short sA[2][16384];
  __shared__ unsigned short sB[2][16384];
  const int tid = threadIdx.x;

  int flat = blockIdx.x + gridDim.x * blockIdx.y;
  const int nwg = gridDim.x * gridDim.y;
  if ((nwg & 7) == 0) flat = (flat & 7) * (nwg >> 3) + (flat >> 3);
  const int m0 = (flat % gridDim.x) << 8;
  const int n0 = (flat / gridDim.x) << 8;

  const int wid = tid >> 6, lane = tid & 63;
  const int wr = wid >> 2, wc = wid & 3;     // 2 (M) x 4 (N) wave grid
  const int lr = lane & 15, lk = lane >> 4;

  const int srow = tid >> 2, scol = (tid & 3) << 3;
  const unsigned short* gA = A + (size_t)(m0 + srow) * K + scol;
  const unsigned short* gB = Bw + (size_t)(n0 + srow) * K + scol;
  const size_t rstep = (size_t)128 * K;

  const int NT = K >> 6;                     // K-tiles

  auto stageA = [&](int buf, int tau, int kk) {
    const int kc = (tau << 6) + (kk << 5);
    unsigned short* d = sA[buf] + kk * 8192 + tid * 8;
    gload16(gA + kc, d);
    gload16(gA + rstep + kc, d + 4096);
  };
  auto stageB = [&](int buf, int tau, int kk) {
    const int kc = (tau << 6) + (kk << 5);
    unsigned short* d = sB[buf] + kk * 8192 + tid * 8;
    gload16(gB + kc, d);
    gload16(gB + rstep + kc, d + 4096);
  };

  // prologue: t0 lo, t0 hi, t1 lo  (order defines the FIFO ledger)
  stageA(0, 0, 0); stageB(0, 0, 0);
  stageA(0, 0, 1); stageB(0, 0, 1);
  stageA(1, 1, 0); stageB(1, 1, 0);

  f32x4 acc[8][4] = {};
  for (int t = 0; t < NT; ++t) {
    const int cb = t & 1;
    // ---- phase 0 : kk = 0 ----
    {
      int tn = t + 1; if (tn >= NT) tn = NT - 1;   // clamp keeps counts uniform
      stageA(cb ^ 1, tn, 1);
      stageB(cb ^ 1, tn, 1);
    }
    asm volatile("s_waitcnt vmcnt(8)" ::: "memory");
    __builtin_amdgcn_s_barrier();
    __builtin_amdgcn_sched_barrier(0);
    {
      bf16x8 af[8], bfr[4];
#pragma unroll
      for (int i = 0; i < 8; ++i)
        af[i] = *reinterpret_cast<const bf16x8*>(
            sA[cb] + ((wr << 7) + (i << 4) + lr) * 32 + (lk << 3));
#pragma unroll
      for (int j = 0; j < 4; ++j)
        bfr[j] = *reinterpret_cast<const bf16x8*>(
            sB[cb] + ((wc << 6) + (j << 4) + lr) * 32 + (lk << 3));
#pragma unroll
      for (int i = 0; i < 8; ++i)
#pragma unroll
        for (int j = 0; j < 4; ++j)
          acc[i][j] = __builtin_amdgcn_mfma_f32_16x16x32_bf16(bfr[j], af[i], acc[i][j], 0, 0, 0);
    }
    __builtin_amdgcn_s_barrier();
    __builtin_amdgcn_sched_barrier(0);
    // ---- phase 1 : kk = 1 ----
    {
      int tn = t + 2; if (tn >= NT) tn = NT - 1;
      stageA(cb, tn, 0);
      stageB(cb, tn, 0);
    }
    asm volatile("s_waitcnt vmcnt(8)" ::: "memory");
    __builtin_amdgcn_s_barrier();
    __builtin_amdgcn_sched_barrier(0);
    {
      bf16x8 af[8], bfr[4];
#pragma unroll
      for (int i = 0; i < 8; ++i)
        af[i] = *reinterpret_cast<const bf16x8*>(
            sA[cb] + 8192 + ((wr << 7) + (i << 4) + lr) * 32 + (lk << 3));
#pragma unroll
      for (int j = 0; j < 4; ++j)
        bfr[j] = *reinterpret_cast<const bf16x8*>(
            sB[cb] + 8192 + ((wc << 6) + (j << 4) + lr) * 32 + (lk << 3));
#pragma unroll
      for (int i = 0; i < 8; ++i)
#pragma unroll
        for (int j = 0; j < 4; ++j)
          acc[i][j] = __builtin_amdgcn_mfma_f32_16x16x32_bf16(bfr[j], af[i], acc[i][j], 0, 0, 0);
    }
    __builtin_amdgcn_s_barrier();
    __builtin_amdgcn_sched_barrier(0);
  }
  asm volatile("s_waitcnt vmcnt(0)" ::: "memory");  // drain before exit

  // C^T fragments: m = mbase + i*16 (lr indexes M); n = nbase + j*16 + e
  const int mbase = m0 + (wr << 7) + lr;
  const int nbase = n0 + (wc << 6) + (lk << 2);
#pragma unroll
  for (int i = 0; i < 8; ++i)
#pragma unroll
    for (int j = 0; j < 4; ++j) {
      const int m = mbase + (i << 4);
      const int n = nbase + (j << 4);
      const size_t off = (size_t)m * N + n;
      f32x4 v = acc[i][j];
      if (EPI == 0) {
        *reinterpret_cast<f32x4*>((float*)Cout + off) = v;
      } else {
        f32x4 o;
#pragma unroll
        for (int e = 0; e < 4; ++e) {
          const float ex = __expf(v[e] * (2.f / 15.f));
          o[e] = 15.f - 30.f / (ex + 1.f);
        }
        *reinterpret_cast<f32x4*>((float*)Cout + off) = o;
      }
    }
}

// ----------------------- gemm512: 128x128 / 8 waves ------------------------
// (R10 structure; chunk-rotation swizzle, conflicts measured 0)

template <int EPI>
__global__ __launch_bounds__(512)
void gemm512(const unsigned short* __restrict__ A,
             const unsigned short* __restrict__ Bw,
             void* __restrict__ Cout,
             int M, int N, int K, int kchunk) {
  __shared__ unsigned short sA[2][128 * 32];
  __shared__ unsigned short sB[2][128 * 32];
  const int tid = threadIdx.x;

  int flat = blockIdx.x + gridDim.x * blockIdx.y;
  const int nwg = gridDim.x * gridDim.y;
  if ((nwg & 7) == 0) flat = (flat & 7) * (nwg >> 3) + (flat >> 3);
  const int m0 = (flat % gridDim.x) << 7;
  const int n0 = (flat / gridDim.x) << 7;
  const int k_begin = blockIdx.z * kchunk;
  int k_end = k_begin + kchunk; if (k_end > K) k_end = K;

  const int wid = tid >> 6, lane = tid & 63;
  const int wr = wid >> 2, wc = wid & 3;           // 2 x 4 wave grid
  const int lr = lane & 15, lk = lane >> 4;

  const int row0 = tid >> 2;
  const int srcch = (((tid & 3) - (tid >> 3)) & 3) << 3;
  const unsigned short* gA = A + (size_t)(m0 + row0) * K + srcch;
  const unsigned short* gB = Bw + (size_t)(n0 + row0) * K + srcch;

  auto stage = [&](int buf, int k0) {
    gload16(gA + k0, sA[buf] + tid * 8);
    gload16(gB + k0, sB[buf] + tid * 8);
  };

  int aoff[4], boff[2];
#pragma unroll
  for (int i = 0; i < 4; ++i) {
    const int r = (wr << 6) + (i << 4) + lr;
    aoff[i] = r * 32 + (((lk + (r >> 1)) & 3) << 3);
  }
#pragma unroll
  for (int j = 0; j < 2; ++j) {
    const int r = (wc << 5) + (j << 4) + lr;
    boff[j] = r * 32 + (((lk + (r >> 1)) & 3) << 3);
  }

  f32x4 acc[4][2] = {};
  int cur = 0;
  stage(0, k_begin);
  __syncthreads();
  for (int k0 = k_begin; k0 < k_end; k0 += 32) {
    bf16x8 af[4], bfr[2];
#pragma unroll
    for (int i = 0; i < 4; ++i)
      af[i] = *reinterpret_cast<const bf16x8*>(sA[cur] + aoff[i]);
#pragma unroll
    for (int j = 0; j < 2; ++j)
      bfr[j] = *reinterpret_cast<const bf16x8*>(sB[cur] + boff[j]);
    const int nxt = k0 + 32;
    if (nxt < k_end) stage(cur ^ 1, nxt);
#pragma unroll
    for (int i = 0; i < 4; ++i)
#pragma unroll
      for (int j = 0; j < 2; ++j)
        acc[i][j] = __builtin_amdgcn_mfma_f32_16x16x32_bf16(bfr[j], af[i], acc[i][j], 0, 0, 0);
    __syncthreads();
    cur ^= 1;
  }
  const int mbase = m0 + (wr << 6) + lr;
  const int nbase = n0 + (wc << 5) + (lk << 2);
  float* outF = (float*)Cout + (size_t)blockIdx.z * M * N;
#pragma unroll
  for (int i = 0; i < 4; ++i)
#pragma unroll
    for (int j = 0; j < 2; ++j) {
      const int m = mbase + (i << 4);
      const int n = nbase + (j << 4);
      const size_t off = (size_t)m * N + n;
      f32x4 v = acc[i][j];
      if (EPI == 0) {
        *reinterpret_cast<f32x4*>(outF + off) = v;
      } else if (EPI == 2) {
        ushort4 u;
        float r0 = v[0] > 0.f ? v[0] : 0.f;
        float r1 = v[1] > 0.f ? v[1] : 0.f;
        float r2 = v[2] > 0.f ? v[2] : 0.f;
        float r3 = v[3] > 0.f ? v[3] : 0.f;
        u.x = f2bf(r0 * r0); u.y = f2bf(r1 * r1);
        u.z = f2bf(r2 * r2); u.w = f2bf(r3 * r3);
        *reinterpret_cast<ushort4*>((unsigned short*)Cout + off) = u;
      } else {
        f32x4 o;
#pragma unroll
        for (int e = 0; e < 4; ++e) {
          const float ex = __expf(v[e] * (2.f / 15.f));
          o[e] = 15.f - 30.f / (ex + 1.f);
        }
        *reinterpret_cast<f32x4*>((float*)Cout + off) = o;
      }
    }
}

// ----------------- legacy 256-thread GEMM (Wo only: 128x64) ----------------

template <int EPI, int NJ>
__global__ __launch_bounds__(256)
void gemm_bf16(const unsigned short* __restrict__ A,
               const unsigned short* __restrict__ Bw,
               const float* __restrict__ Cin, void* __restrict__ Cout,
               int M, int N, int K, int kchunk) {
  constexpr int BN = NJ * 32;
  __shared__ unsigned short sA[2][128 * 32];
  __shared__ unsigned short sB[2][BN * 32];
  const int tid = threadIdx.x;

  int flat = blockIdx.x + gridDim.x * blockIdx.y;
  const int nwg = gridDim.x * gridDim.y;
  if ((nwg & 7) == 0) flat = (flat & 7) * (nwg >> 3) + (flat >> 3);
  const int m0 = (flat % gridDim.x) << 7;
  const int n0 = (flat / gridDim.x) * BN;
  const int k_begin = blockIdx.z * kchunk;
  int k_end = k_begin + kchunk; if (k_end > K) k_end = K;

  const int wid = tid >> 6, lane = tid & 63;
  const int wr = wid >> 1, wc = wid & 1;
  const int lr = lane & 15, lk = lane >> 4;

  const int row0 = tid >> 2, ch0 = (tid & 3) << 3;
  const unsigned short* gA0 = A + (size_t)(m0 + row0) * K + ch0;
  const unsigned short* gA1 = gA0 + (size_t)64 * K;
  const unsigned short* gB0 = Bw + (size_t)(n0 + row0) * K + ch0;
  const int lofs = wid << 9;

  auto stage = [&](int buf, int k0) {
    gload16(gA0 + k0, sA[buf] + lofs);
    gload16(gA1 + k0, sA[buf] + lofs + 2048);
    gload16(gB0 + k0, sB[buf] + lofs);
  };

  f32x4 acc[4][NJ] = {};
  int cur = 0;
  stage(0, k_begin);
  __syncthreads();
  for (int k0 = k_begin; k0 < k_end; k0 += 32) {
    bf16x8 af[4], bfr[NJ];
#pragma unroll
    for (int i = 0; i < 4; ++i)
      af[i] = *reinterpret_cast<const bf16x8*>(sA[cur] + ((wr << 6) + (i << 4) + lr) * 32 + (lk << 3));
#pragma unroll
    for (int j = 0; j < NJ; ++j)
      bfr[j] = *reinterpret_cast<const bf16x8*>(sB[cur] + (wc * (BN / 2) + (j << 4) + lr) * 32 + (lk << 3));
    const int nxt = k0 + 32;
    if (nxt < k_end) stage(cur ^ 1, nxt);
#pragma unroll
    for (int i = 0; i < 4; ++i)
#pragma unroll
      for (int j = 0; j < NJ; ++j)
        acc[i][j] = __builtin_amdgcn_mfma_f32_16x16x32_bf16(bfr[j], af[i], acc[i][j], 0, 0, 0);
    __syncthreads();
    cur ^= 1;
  }
  const int mbase = m0 + (wr << 6) + lr;
  const int nbase = n0 + wc * (BN / 2) + (lk << 2);
  float* outF = (float*)Cout + (size_t)blockIdx.z * M * N;
#pragma unroll
  for (int i = 0; i < 4; ++i)
#pragma unroll
    for (int j = 0; j < NJ; ++j) {
      const int m = mbase + (i << 4);
      const int n = nbase + (j << 4);
      const size_t off = (size_t)m * N + n;
      *reinterpret_cast<f32x4*>(outF + off) = acc[i][j];
    }
  (void)Cin;
}

// ------------------------------- launcher ----------------------------------

extern "C" void kernel_launch(void* const* d_in, const int* in_sizes, int n_in,
                              void* d_out, int out_size, void* d_ws, size_t ws_size,
                              hipStream_t stream) {
  (void)in_sizes; (void)n_in; (void)out_size; (void)ws_size;
  const int*   ids  = (const int*)  d_in[0];
  const float* wte  = (const float*)d_in[1];
  const float* Wq   = (const float*)d_in[2];
  const float* Wk   = (const float*)d_in[3];
  const float* Wv   = (const float*)d_in[4];
  const float* Wo   = (const float*)d_in[5];
  const float* Wfc  = (const float*)d_in[6];
  const float* Wmp  = (const float*)d_in[7];
  const float* VeT  = (const float*)d_in[8];
  const float* VeG  = (const float*)d_in[9];
  const float* LmW  = (const float*)d_in[10];
  const float* ResC = (const float*)d_in[11];
  const float* X0C  = (const float*)d_in[12];
  const float* SmW  = (const float*)d_in[13];
  const float* SmL  = (const float*)d_in[14];

  char* p = (char*)d_ws;
  auto alloc = [&](size_t bytes) -> char* {
    char* r = p; p += (bytes + 255) & ~(size_t)255; return r;
  };
  float* x  = (float*)alloc((size_t)2048 * 1024 * 4);
  float* x0 = (float*)alloc((size_t)2048 * 1024 * 4);
  unsigned short* xn = (unsigned short*)alloc((size_t)2048 * 1024 * 2);
  unsigned short* hidden = (unsigned short*)alloc((size_t)2048 * 4096 * 2);
  float* qkvp = (float*)alloc((size_t)2 * 2048 * 1536 * 4);   // qkv split-K partials
  float* wop  = (float*)alloc((size_t)2 * 2048 * 1024 * 4);   // Wo split-K partials
  float* mpp  = (float*)alloc((size_t)4 * 2048 * 1024 * 4);   // MP split-K partials
  unsigned short* qbuf = (unsigned short*)alloc((size_t)2048 * 1024 * 2);
  unsigned short* kbuf = (unsigned short*)alloc((size_t)2048 * 256 * 2);
  unsigned short* vbuf = (unsigned short*)alloc((size_t)2048 * 256 * 2);
  unsigned short* vtb  = (unsigned short*)alloc((size_t)2048 * 256 * 2);
  unsigned short* ybuf = (unsigned short*)alloc((size_t)2048 * 1024 * 2);
  float* cost = (float*)alloc((size_t)1024 * 32 * 4);
  float* sint = (float*)alloc((size_t)1024 * 32 * 4);
  unsigned short* wqkv = (unsigned short*)alloc((size_t)6 * 1536 * 1024 * 2);
  unsigned short* wo   = (unsigned short*)alloc((size_t)6 * 1024 * 1024 * 2);
  unsigned short* wfc  = (unsigned short*)alloc((size_t)6 * 4096 * 1024 * 2);
  unsigned short* wmp  = (unsigned short*)alloc((size_t)6 * 1024 * 4096 * 2);
  unsigned short* wlm  = (unsigned short*)alloc((size_t)32000 * 1024 * 2);

  prep_weights_kernel<<<48256, 256, 0, stream>>>(Wq, Wk, Wv, Wo, Wfc, Wmp, LmW,
                                                 wqkv, wo, wfc, wmp, wlm);
  rope_tab_kernel<<<128, 256, 0, stream>>>(cost, sint);
  embed_kernel<<<512, 256, 0, stream>>>(ids, wte, SmW, SmL, ResC, X0C, x, x0, xn);

  static const int WIN[6] = {256, 1024, 256, 1024, 256, 1024};
  for (int l = 0; l < 6; ++l) {
    if (l > 0)
      rmsnorm_kernel<<<512, 256, 0, stream>>>(x, x0, mpp, 4, ResC, X0C, l, 1, xn);
    // QKV: split-K x2 -> two partial planes (summed inside qkv_post)
    gemm512<0><<<dim3(16, 12, 2), 512, 0, stream>>>(xn, wqkv + (size_t)l * 1536 * 1024,
                                                    qkvp, 2048, 1536, 1024, 512);
    const float* vtab = nullptr; const float* vgw = nullptr;
    if (l == 1 || l == 3 || l == 5) {
      const int vi = (l - 1) / 2;
      vtab = VeT + (size_t)vi * 32000 * 256;
      vgw  = VeG + vi * 48;
    }
    qkv_post_kernel<<<512, 256, 0, stream>>>(qkvp, qkvp + (size_t)2048 * 1536, xn, ids,
                                             vtab, vgw, cost, sint, qbuf, kbuf, vbuf);
    vtrans_kernel<<<dim3(16, 8), 256, 0, stream>>>(vbuf, vtb);
    attn_kernel<<<dim3(64, 16, 2), 64, 0, stream>>>(qbuf, kbuf, vtb, ybuf, WIN[l]);
    // Wo: split-K x2 -> partials (reduced + added to x by next rmsnorm)
    gemm_bf16<0, 2><<<dim3(16, 16, 2), 256, 0, stream>>>(ybuf, wo + (size_t)l * 1024 * 1024,
                                                         nullptr, wop, 2048, 1024, 1024, 512);
    rmsnorm_kernel<<<512, 256, 0, stream>>>(x, x0, wop, 2, ResC, X0C, l, 0, xn);
    gemm512<2><<<dim3(16, 32), 512, 0, stream>>>(xn, wfc + (size_t)l * 4096 * 1024,
                                                 hidden, 2048, 4096, 1024, 1024);
    // MP: split-K x4 (K=4096) -> partials (reduced by next layer's rmsnorm)
    gemm512<0><<<dim3(16, 8, 4), 512, 0, stream>>>(hidden, wmp + (size_t)l * 1024 * 4096,
                                                   mpp, 2048, 1024, 4096, 1024);
  }
  rmsnorm_kernel<<<512, 256, 0, stream>>>(x, x0, mpp, 4, ResC, X0C, 0, 0, xn);
  // LM head: 256x256 counted-vmcnt pipeline, grid 8 x 125 = 1000 blocks
  gemm256<3><<<dim3(8, 125), 512, 0, stream>>>(xn, wlm, (float*)d_out,
                                               2048, 32000, 1024);
}

// Round 12
// 1375.710 us; speedup vs baseline: 1.0103x; 1.0103x over previous
//
#include <hip/hip_runtime.h>
#include <stdint.h>
#include <math.h>

// ---------------------------------------------------------------------------
// NanochatMiniLM forward on MI355X. Round 12: R11's counted-vmcnt 256² port
// regressed (128KB LDS -> 1 block/CU, no TLP). This round keeps the PROVEN
// 2-phase schedule (stage(t+1); MFMA; one __syncthreads — R5/R10) and takes
// only the tile-size lever: LM head = 256x256, BK=32, 64KB LDS (2 blocks/CU),
// 32 MFMA per barrier (4x better drain amortization than 128²), R10
// chunk-rotation swizzle (measured conflicts = 0). Everything else = R10.
// B=2 T=1024 D=1024 H=16 KV=4 HD=64 L=6 VP=32000, windows {256,1024,...}
// ---------------------------------------------------------------------------

using bf16x8 = __attribute__((ext_vector_type(8))) short;   // 8 bf16 (4 VGPRs)
using f32x4  = __attribute__((ext_vector_type(4))) float;   // 4 f32 acc

#define DEV static __device__ __forceinline__

DEV unsigned short f2bf(float f) {            // RNE f32 -> bf16 bits
  unsigned int x = __builtin_bit_cast(unsigned int, f);
  x += 0x7fffu + ((x >> 16) & 1u);
  return (unsigned short)(x >> 16);
}
DEV float bf2f(unsigned short u) {
  return __builtin_bit_cast(float, (unsigned int)u << 16);
}
DEV unsigned int packbf2(float a, float b) {
  return (unsigned int)f2bf(a) | ((unsigned int)f2bf(b) << 16);
}

// async global->LDS, 16B per lane; LDS dest is wave-uniform base + lane*16
DEV void gload16(const unsigned short* g, unsigned short* l) {
  __builtin_amdgcn_global_load_lds(
      (__attribute__((address_space(1))) void*)const_cast<unsigned short*>(g),
      (__attribute__((address_space(3))) void*)l, 16, 0, 0);
}

// ------------------- merged weight conversion (one launch) -----------------

extern "C" __global__ __launch_bounds__(256)
void prep_weights_kernel(const float* __restrict__ Wq, const float* __restrict__ Wk,
                         const float* __restrict__ Wv, const float* __restrict__ Wo,
                         const float* __restrict__ Wfc, const float* __restrict__ Wmp,
                         const float* __restrict__ LmW,
                         unsigned short* __restrict__ wqkv, unsigned short* __restrict__ wo,
                         unsigned short* __restrict__ wfc, unsigned short* __restrict__ wmp,
                         unsigned short* __restrict__ wlm) {
  const long v = (long)blockIdx.x * 256 + threadIdx.x;   // vector index
  const long S0 = 1179648, S1 = S0 + 786432, S2 = S1 + 3145728,
             S3 = S2 + 3145728, S4 = S3 + 4096000;
  const float* src; unsigned short* dst;
  if (v < S0) {
    const long i = v * 8;
    const int c = (int)(i & 1023);
    const int row = (int)(i >> 10);
    const int l = row / 1536, r = row - l * 1536;
    if (r < 1024)      src = Wq + ((size_t)l * 1024 + r) * 1024 + c;
    else if (r < 1280) src = Wk + ((size_t)l * 256 + (r - 1024)) * 1024 + c;
    else               src = Wv + ((size_t)l * 256 + (r - 1280)) * 1024 + c;
    dst = wqkv + i;
  } else if (v < S1) {
    const long i = (v - S0) * 8; src = Wo + i;  dst = wo + i;
  } else if (v < S2) {
    const long i = (v - S1) * 8; src = Wfc + i; dst = wfc + i;
  } else if (v < S3) {
    const long i = (v - S2) * 8; src = Wmp + i; dst = wmp + i;
  } else if (v < S4) {
    const long i = (v - S3) * 8; src = LmW + i; dst = wlm + i;
  } else {
    return;
  }
  const float4 a = *reinterpret_cast<const float4*>(src);
  const float4 b = *reinterpret_cast<const float4*>(src + 4);
  uint4 u;
  u.x = packbf2(a.x, a.y); u.y = packbf2(a.z, a.w);
  u.z = packbf2(b.x, b.y); u.w = packbf2(b.z, b.w);
  *reinterpret_cast<uint4*>(dst) = u;
}

// ------------------------------- rope tables -------------------------------

extern "C" __global__ __launch_bounds__(256)
void rope_tab_kernel(float* __restrict__ cost, float* __restrict__ sint) {
  const int idx = blockIdx.x * 256 + threadIdx.x;   // t*32 + i, 32768 total
  const int t = idx >> 5, i = idx & 31;
  const double inv = exp(((double)i * (-1.0 / 32.0)) * log(100000.0));
  const double f = (double)t * inv;
  cost[idx] = (float)cos(f);
  sint[idx] = (float)sin(f);
}

// ------------- embedding + rms + smear + fused l=0 combine+rms -------------

extern "C" __global__ __launch_bounds__(256)
void embed_kernel(const int* __restrict__ ids, const float* __restrict__ wte,
                  const float* __restrict__ smear_w, const float* __restrict__ smear_l,
                  const float* __restrict__ residc, const float* __restrict__ x0c,
                  float* __restrict__ x, float* __restrict__ x0,
                  unsigned short* __restrict__ xn) {
  const int wid = threadIdx.x >> 6, lane = threadIdx.x & 63;
  const int tok = blockIdx.x * 4 + wid;
  const int t = tok & 1023;
  const float eps = 1.1920929e-7f;

  const float* wrow = wte + (size_t)ids[tok] * 1024;
  float4 v[4];
  float ss = 0.f;
#pragma unroll
  for (int i = 0; i < 4; ++i) {
    v[i] = *reinterpret_cast<const float4*>(wrow + i * 256 + lane * 4);
    ss += v[i].x * v[i].x + v[i].y * v[i].y + v[i].z * v[i].z + v[i].w * v[i].w;
  }
#pragma unroll
  for (int m = 1; m < 64; m <<= 1) ss += __shfl_xor(ss, m);
  const float sc = 1.f / sqrtf(ss * (1.f / 1024.f) + eps);

  float4 pv[4];
#pragma unroll
  for (int i = 0; i < 4; ++i) { pv[i].x = 0.f; pv[i].y = 0.f; pv[i].z = 0.f; pv[i].w = 0.f; }
  float scp = 0.f, gate = 0.f;
  if (t > 0) {
    const float* prow = wte + (size_t)ids[tok - 1] * 1024;
    float ssp = 0.f;
#pragma unroll
    for (int i = 0; i < 4; ++i) {
      pv[i] = *reinterpret_cast<const float4*>(prow + i * 256 + lane * 4);
      ssp += pv[i].x * pv[i].x + pv[i].y * pv[i].y + pv[i].z * pv[i].z + pv[i].w * pv[i].w;
    }
#pragma unroll
    for (int m = 1; m < 64; m <<= 1) ssp += __shfl_xor(ssp, m);
    scp = 1.f / sqrtf(ssp * (1.f / 1024.f) + eps);
    float gp = 0.f;
    if (lane < 6) {
      gp = v[0].x * smear_w[lane * 4] + v[0].y * smear_w[lane * 4 + 1] +
           v[0].z * smear_w[lane * 4 + 2] + v[0].w * smear_w[lane * 4 + 3];
      gp *= sc;
    }
#pragma unroll
    for (int m = 1; m < 64; m <<= 1) gp += __shfl_xor(gp, m);
    gate = smear_l[0] / (1.f + __expf(-gp));
  }
  const float a0 = residc[0], b0 = x0c[0];
  float4 y[4];
  float ssy = 0.f;
#pragma unroll
  for (int i = 0; i < 4; ++i) {
    const int c = i * 256 + lane * 4;
    float4 o;
    o.x = v[i].x * sc + gate * pv[i].x * scp;
    o.y = v[i].y * sc + gate * pv[i].y * scp;
    o.z = v[i].z * sc + gate * pv[i].z * scp;
    o.w = v[i].w * sc + gate * pv[i].w * scp;
    *reinterpret_cast<float4*>(x0 + (size_t)tok * 1024 + c) = o;
    float4 yy;
    yy.x = a0 * o.x + b0 * o.x; yy.y = a0 * o.y + b0 * o.y;
    yy.z = a0 * o.z + b0 * o.z; yy.w = a0 * o.w + b0 * o.w;
    *reinterpret_cast<float4*>(x + (size_t)tok * 1024 + c) = yy;
    y[i] = yy;
    ssy += yy.x * yy.x + yy.y * yy.y + yy.z * yy.z + yy.w * yy.w;
  }
#pragma unroll
  for (int m = 1; m < 64; m <<= 1) ssy += __shfl_xor(ssy, m);
  const float scy = 1.f / sqrtf(ssy * (1.f / 1024.f) + eps);
#pragma unroll
  for (int i = 0; i < 4; ++i) {
    const int c = i * 256 + lane * 4;
    ushort4 u;
    u.x = f2bf(y[i].x * scy); u.y = f2bf(y[i].y * scy);
    u.z = f2bf(y[i].z * scy); u.w = f2bf(y[i].w * scy);
    *reinterpret_cast<ushort4*>(xn + (size_t)tok * 1024 + c) = u;
  }
}

// ------------- residual mix + split-K partial reduce + rmsnorm -------------

extern "C" __global__ __launch_bounds__(256)
void rmsnorm_kernel(float* __restrict__ x, const float* __restrict__ x0,
                    const float* __restrict__ parts, int np,
                    const float* __restrict__ residc, const float* __restrict__ x0c,
                    int layer, int combine, unsigned short* __restrict__ xn) {
  const int wid = threadIdx.x >> 6, lane = threadIdx.x & 63;
  const int tok = blockIdx.x * 4 + wid;
  float* xr = x + (size_t)tok * 1024;
  const float* x0r = x0 + (size_t)tok * 1024;
  float a = 1.f, bb = 0.f;
  if (combine) { a = residc[layer]; bb = x0c[layer]; }
  float4 v[4];
  float ss = 0.f;
#pragma unroll
  for (int i = 0; i < 4; ++i) {
    const int c = i * 256 + lane * 4;
    float4 xv = *reinterpret_cast<const float4*>(xr + c);
    for (int pi = 0; pi < np; ++pi) {
      const float4 pv = *reinterpret_cast<const float4*>(
          parts + (size_t)pi * 2048 * 1024 + (size_t)tok * 1024 + c);
      xv.x += pv.x; xv.y += pv.y; xv.z += pv.z; xv.w += pv.w;
    }
    if (combine) {
      const float4 ov = *reinterpret_cast<const float4*>(x0r + c);
      xv.x = a * xv.x + bb * ov.x; xv.y = a * xv.y + bb * ov.y;
      xv.z = a * xv.z + bb * ov.z; xv.w = a * xv.w + bb * ov.w;
    }
    if (combine || np > 0) *reinterpret_cast<float4*>(xr + c) = xv;
    v[i] = xv;
    ss += xv.x * xv.x + xv.y * xv.y + xv.z * xv.z + xv.w * xv.w;
  }
#pragma unroll
  for (int m = 1; m < 64; m <<= 1) ss += __shfl_xor(ss, m);
  const float sc = 1.f / sqrtf(ss * (1.f / 1024.f) + 1.1920929e-7f);
#pragma unroll
  for (int i = 0; i < 4; ++i) {
    const int c = i * 256 + lane * 4;
    ushort4 u;
    u.x = f2bf(v[i].x * sc); u.y = f2bf(v[i].y * sc);
    u.z = f2bf(v[i].z * sc); u.w = f2bf(v[i].w * sc);
    *reinterpret_cast<ushort4*>(xn + (size_t)tok * 1024 + c) = u;
  }
}

// ------------------- qkv post: rope + rms + ve-gate -> bf16 ----------------

extern "C" __global__ __launch_bounds__(256)
void qkv_post_kernel(const float* __restrict__ qkv0, const float* __restrict__ qkv1,
                     const unsigned short* __restrict__ xn,
                     const int* __restrict__ ids,
                     const float* __restrict__ ve_tab, const float* __restrict__ ve_gate_w,
                     const float* __restrict__ cost, const float* __restrict__ sint,
                     unsigned short* __restrict__ qb, unsigned short* __restrict__ kbuf,
                     unsigned short* __restrict__ vb) {
  const int wid = threadIdx.x >> 6, lane = threadIdx.x & 63;
  const int tok = blockIdx.x * 4 + wid;
  const int t = tok & 1023;
  const float eps = 1.1920929e-7f;
  const float* rowA = qkv0 + (size_t)tok * 1536;
  const float* rowB = qkv1 + (size_t)tok * 1536;
  const bool x1half = (lane & 2) == 0;   // lane%4 in {0,1}: x1; {2,3}: x2
  const int i0 = (lane & 1) << 4;        // rotary index base within half

  // ---- Q: 16 heads * 64, scale = 1.2/8 folded in ----
  {
    float v[16], p[16];
    {
      const float4* ra = reinterpret_cast<const float4*>(rowA + lane * 16);
      const float4* rb = reinterpret_cast<const float4*>(rowB + lane * 16);
#pragma unroll
      for (int i = 0; i < 4; ++i) {
        const float4 qa = ra[i], qb4 = rb[i];
        v[i * 4] = qa.x + qb4.x; v[i * 4 + 1] = qa.y + qb4.y;
        v[i * 4 + 2] = qa.z + qb4.z; v[i * 4 + 3] = qa.w + qb4.w;
      }
    }
#pragma unroll
    for (int i = 0; i < 16; ++i) p[i] = __shfl_xor(v[i], 2);
    float out[16]; float ssq = 0.f;
#pragma unroll
    for (int i = 0; i < 16; ++i) {
      const float c = cost[t * 32 + i0 + i];
      const float s = sint[t * 32 + i0 + i];
      out[i] = x1half ? (v[i] * c + p[i] * s) : (v[i] * c - p[i] * s);
      ssq += out[i] * out[i];
    }
    ssq += __shfl_xor(ssq, 1);
    ssq += __shfl_xor(ssq, 2);
    const float sc = 0.15f / sqrtf(ssq * (1.f / 64.f) + eps);
#pragma unroll
    for (int i = 0; i < 16; i += 4) {
      ushort4 u;
      u.x = f2bf(out[i] * sc); u.y = f2bf(out[i + 1] * sc);
      u.z = f2bf(out[i + 2] * sc); u.w = f2bf(out[i + 3] * sc);
      *reinterpret_cast<ushort4*>(qb + (size_t)tok * 1024 + lane * 16 + i) = u;
    }
  }
  const int kl = lane & 15;  // lanes 16-63 mirror 0-15 (keeps shfl uniform)
  // ---- K: 4 kv heads * 64, scale 1.2 ----
  {
    float v[16], p[16];
    {
      const float4* ra = reinterpret_cast<const float4*>(rowA + 1024 + kl * 16);
      const float4* rb = reinterpret_cast<const float4*>(rowB + 1024 + kl * 16);
#pragma unroll
      for (int i = 0; i < 4; ++i) {
        const float4 qa = ra[i], qb4 = rb[i];
        v[i * 4] = qa.x + qb4.x; v[i * 4 + 1] = qa.y + qb4.y;
        v[i * 4 + 2] = qa.z + qb4.z; v[i * 4 + 3] = qa.w + qb4.w;
      }
    }
#pragma unroll
    for (int i = 0; i < 16; ++i) p[i] = __shfl_xor(v[i], 2);
    float out[16]; float ssq = 0.f;
#pragma unroll
    for (int i = 0; i < 16; ++i) {
      const float c = cost[t * 32 + i0 + i];
      const float s = sint[t * 32 + i0 + i];
      out[i] = x1half ? (v[i] * c + p[i] * s) : (v[i] * c - p[i] * s);
      ssq += out[i] * out[i];
    }
    ssq += __shfl_xor(ssq, 1);
    ssq += __shfl_xor(ssq, 2);
    const float sc = 1.2f / sqrtf(ssq * (1.f / 64.f) + eps);
    if (lane < 16) {
#pragma unroll
      for (int i = 0; i < 16; i += 4) {
        ushort4 u;
        u.x = f2bf(out[i] * sc); u.y = f2bf(out[i + 1] * sc);
        u.z = f2bf(out[i + 2] * sc); u.w = f2bf(out[i + 3] * sc);
        *reinterpret_cast<ushort4*>(kbuf + (size_t)tok * 256 + kl * 16 + i) = u;
      }
    }
  }
  // ---- V: optional value-embedding gate ----
  {
    float v[16];
    {
      const float4* ra = reinterpret_cast<const float4*>(rowA + 1280 + kl * 16);
      const float4* rb = reinterpret_cast<const float4*>(rowB + 1280 + kl * 16);
#pragma unroll
      for (int i = 0; i < 4; ++i) {
        const float4 qa = ra[i], qb4 = rb[i];
        v[i * 4] = qa.x + qb4.x; v[i * 4 + 1] = qa.y + qb4.y;
        v[i * 4 + 2] = qa.z + qb4.z; v[i * 4 + 3] = qa.w + qb4.w;
      }
    }
    if (ve_tab != nullptr) {
      const int kvh = kl >> 2;
      float g = 0.f;
#pragma unroll
      for (int c = 0; c < 12; ++c)
        g += bf2f(xn[(size_t)tok * 1024 + c]) * ve_gate_w[kvh * 12 + c];
      g = 3.f / (1.f + __expf(-g));
      const float* ver = ve_tab + (size_t)ids[tok] * 256 + kl * 16;
#pragma unroll
      for (int i = 0; i < 16; ++i) v[i] += g * ver[i];
    }
    if (lane < 16) {
#pragma unroll
      for (int i = 0; i < 16; i += 4) {
        ushort4 u;
        u.x = f2bf(v[i]); u.y = f2bf(v[i + 1]); u.z = f2bf(v[i + 2]); u.w = f2bf(v[i + 3]);
        *reinterpret_cast<ushort4*>(vb + (size_t)tok * 256 + kl * 16 + i) = u;
      }
    }
  }
}

// ---------------- V transpose: vb[b][t][kv*64+d] -> vt[b*4+kv][d][t] -------

extern "C" __global__ __launch_bounds__(256)
void vtrans_kernel(const unsigned short* __restrict__ vb, unsigned short* __restrict__ vt) {
  __shared__ unsigned short tile[64][72];
  const int t0 = blockIdx.x << 6;
  const int bk = blockIdx.y;               // b*4 + kv
  const int tid = threadIdx.x;
  {
    const int r = tid >> 2, cs = (tid & 3) << 4;
    const unsigned short* src = vb + ((size_t)((bk >> 2) * 1024 + t0 + r)) * 256 + (bk & 3) * 64 + cs;
    *reinterpret_cast<uint4*>(&tile[r][cs]) = *reinterpret_cast<const uint4*>(src);
    *reinterpret_cast<uint4*>(&tile[r][cs + 8]) = *reinterpret_cast<const uint4*>(src + 8);
  }
  __syncthreads();
  {
    const int d = tid >> 2, ts = (tid & 3) << 4;
    unsigned int w[8];
#pragma unroll
    for (int i = 0; i < 8; ++i)
      w[i] = (unsigned int)tile[ts + 2 * i][d] | ((unsigned int)tile[ts + 2 * i + 1][d] << 16);
    unsigned short* dst = vt + ((size_t)bk * 64 + d) * 1024 + t0 + ts;
    uint4 u0; u0.x = w[0]; u0.y = w[1]; u0.z = w[2]; u0.w = w[3];
    uint4 u1; u1.x = w[4]; u1.y = w[5]; u1.z = w[6]; u1.w = w[7];
    *reinterpret_cast<uint4*>(dst) = u0;
    *reinterpret_cast<uint4*>(dst + 8) = u1;
  }
}

// --------------------------- flash attention -------------------------------

extern "C" __global__ __launch_bounds__(64)
void attn_kernel(const unsigned short* __restrict__ qb,
                 const unsigned short* __restrict__ kb,
                 const unsigned short* __restrict__ vt,
                 unsigned short* __restrict__ y, int W) {
  __shared__ unsigned short p_lds[16 * 32];
  const int lane = threadIdx.x;
  const int q0 = blockIdx.x << 4;
  const int h = blockIdx.y;
  const int b = blockIdx.z;
  const int kv = h >> 2;
  const int lr = lane & 15, lk = lane >> 4;

  bf16x8 qf0, qf1;
  {
    const unsigned short* qrow = qb + ((size_t)(b * 1024 + q0 + lr)) * 1024 + h * 64 + (lk << 3);
    qf0 = *reinterpret_cast<const bf16x8*>(qrow);
    qf1 = *reinterpret_cast<const bf16x8*>(qrow + 32);
  }
  f32x4 acc[4] = {};
  float m_run = -3e38f, l_run = 0.f;
  int kstart = q0 - W + 1; if (kstart < 0) kstart = 0;
  kstart &= ~31;
  const int qq = q0 + lr;

  for (int kb0 = kstart; kb0 < q0 + 16; kb0 += 32) {
    f32x4 st[2];
#pragma unroll
    for (int s = 0; s < 2; ++s) {
      const unsigned short* krow = kb + ((size_t)(b * 1024 + kb0 + (s << 4) + lr)) * 256 + kv * 64 + (lk << 3);
      bf16x8 kf0 = *reinterpret_cast<const bf16x8*>(krow);
      bf16x8 kf1 = *reinterpret_cast<const bf16x8*>(krow + 32);
      f32x4 z = {0.f, 0.f, 0.f, 0.f};
      z = __builtin_amdgcn_mfma_f32_16x16x32_bf16(kf0, qf0, z, 0, 0, 0);
      st[s] = __builtin_amdgcn_mfma_f32_16x16x32_bf16(kf1, qf1, z, 0, 0, 0);
    }
    float sv[8];
    float bm = -3e38f;
#pragma unroll
    for (int s = 0; s < 2; ++s)
#pragma unroll
      for (int j = 0; j < 4; ++j) {
        const int key = kb0 + (s << 4) + (lk << 2) + j;
        const bool valid = (key <= qq) && (qq - key < W);
        const float xx = valid ? st[s][j] : -3e38f;
        sv[s * 4 + j] = xx;
        bm = fmaxf(bm, xx);
      }
    bm = fmaxf(bm, __shfl_xor(bm, 16));
    bm = fmaxf(bm, __shfl_xor(bm, 32));
    const float m_new = fmaxf(m_run, bm);
    const float alpha = __expf(m_run - m_new);
    float psum = 0.f;
    unsigned short pbv[8];
#pragma unroll
    for (int s = 0; s < 2; ++s)
#pragma unroll
      for (int j = 0; j < 4; ++j) {
        const int key = kb0 + (s << 4) + (lk << 2) + j;
        const bool valid = (key <= qq) && (qq - key < W);
        const float pv = valid ? __expf(sv[s * 4 + j] - m_new) : 0.f;
        psum += pv;
        pbv[s * 4 + j] = f2bf(pv);
      }
    psum += __shfl_xor(psum, 16);
    psum += __shfl_xor(psum, 32);
    l_run = l_run * alpha + psum;
    m_run = m_new;

    __syncthreads();  // WAR vs previous iteration's reads
    {
      ushort4 u0, u1;
      u0.x = pbv[0]; u0.y = pbv[1]; u0.z = pbv[2]; u0.w = pbv[3];
      u1.x = pbv[4]; u1.y = pbv[5]; u1.z = pbv[6]; u1.w = pbv[7];
      *reinterpret_cast<ushort4*>(p_lds + lr * 32 + (lk << 2)) = u0;
      *reinterpret_cast<ushort4*>(p_lds + lr * 32 + 16 + (lk << 2)) = u1;
    }
    __syncthreads();
    const bf16x8 pf = *reinterpret_cast<const bf16x8*>(p_lds + lr * 32 + (lk << 3));
    float al[4];
#pragma unroll
    for (int j = 0; j < 4; ++j) al[j] = __shfl(alpha, (lk << 2) + j);
#pragma unroll
    for (int d = 0; d < 4; ++d) {
      const unsigned short* vrow = vt + ((size_t)((b * 4 + kv) * 64 + (d << 4) + lr)) * 1024 + kb0 + (lk << 3);
      const bf16x8 vf = *reinterpret_cast<const bf16x8*>(vrow);
#pragma unroll
      for (int j = 0; j < 4; ++j) acc[d][j] *= al[j];
      acc[d] = __builtin_amdgcn_mfma_f32_16x16x32_bf16(pf, vf, acc[d], 0, 0, 0);
    }
  }
  float linv[4];
#pragma unroll
  for (int j = 0; j < 4; ++j) linv[j] = 1.f / __shfl(l_run, (lk << 2) + j);
#pragma unroll
  for (int d = 0; d < 4; ++d)
#pragma unroll
    for (int j = 0; j < 4; ++j) {
      const int qrow = q0 + (lk << 2) + j;
      y[((size_t)(b * 1024 + qrow)) * 1024 + h * 64 + (d << 4) + lr] = f2bf(acc[d][j] * linv[j]);
    }
}

// -------------- gemm256b: 256x256 / BK=32 / 8 waves / 2-phase --------------
// Same proven schedule as gemm512 (stage(t+1) before MFMA, ONE __syncthreads
// per K-step); tile raised to 256x256 so each barrier drain amortizes over
// 32 MFMAs (4x gemm512). LDS 64KB (2 blocks/CU). Chunk-rotation swizzle as
// in gemm512 (LDS slot (row,cp) holds global chunk (cp-row/2)&3; read uses
// cp=(lk+row/2)&3; rows r and r+128 share srcch since 128%4==0).
// Staging: 4 gload16/thread (A rows tid>>2 & +128, B same); LDS addr =
// row*32 + cp*8 shorts, linear per round (wave-uniform + lane*16 ✓).
// acc[8][4] = 128 AGPR/lane; wr=wid>>2 (2 M-groups x 128), wc=wid&3 (4
// N-groups x 64). C^T epilogue: m = mbase+i*16, n = nbase+j*16+e.
// EPI: 0 f32, 3 softcap f32. XCD swizzle when nwg%8==0.

template <int EPI>
__global__ __launch_bounds__(512)
void gemm256b(const unsigned short* __restrict__ A,
              const unsigned short* __restrict__ Bw,
              void* __restrict__ Cout, int M, int N, int K) {
  __shared__ unsigned short sA[2][256 * 32];
  __shared__ unsigned short sB[2][256 * 32];
  const int tid = threadIdx.x;

  int flat = blockIdx.x + gridDim.x * blockIdx.y;
  const int nwg = gridDim.x * gridDim.y;
  if ((nwg & 7) == 0) flat = (flat & 7) * (nwg >> 3) + (flat >> 3);
  const int m0 = (flat % gridDim.x) << 8;
  const int n0 = (flat / gridDim.x) << 8;

  const int wid = tid >> 6, lane = tid & 63;
  const int wr = wid >> 2, wc = wid & 3;     // 2 (M) x 4 (N) wave grid
  const int lr = lane & 15, lk = lane >> 4;

  // staging: rows row0 and row0+128; source chunk inverse-rotated
  const int row0 = tid >> 2;
  const int srcch = (((tid & 3) - (tid >> 3)) & 3) << 3;   // same for row0+128
  const unsigned short* gA = A + (size_t)(m0 + row0) * K + srcch;
  const unsigned short* gB = Bw + (size_t)(n0 + row0) * K + srcch;
  const size_t rstep = (size_t)128 * K;

  auto stage = [&](int buf, int k0) {
    gload16(gA + k0, sA[buf] + tid * 8);
    gload16(gA + rstep + k0, sA[buf] + tid * 8 + 4096);
    gload16(gB + k0, sB[buf] + tid * 8);
    gload16(gB + rstep + k0, sB[buf] + tid * 8 + 4096);
  };

  // read offsets (shorts), loop-invariant: row*32 + ((lk + row/2)&3)*8
  int aoff[8], boff[4];
#pragma unroll
  for (int i = 0; i < 8; ++i) {
    const int r = (wr << 7) + (i << 4) + lr;
    aoff[i] = r * 32 + (((lk + (r >> 1)) & 3) << 3);
  }
#pragma unroll
  for (int j = 0; j < 4; ++j) {
    const int r = (wc << 6) + (j << 4) + lr;
    boff[j] = r * 32 + (((lk + (r >> 1)) & 3) << 3);
  }

  f32x4 acc[8][4] = {};
  int cur = 0;
  stage(0, 0);
  __syncthreads();                        // drain prologue stage
  for (int k0 = 0; k0 < K; k0 += 32) {
    bf16x8 af[8], bfr[4];
#pragma unroll
    for (int i = 0; i < 8; ++i)
      af[i] = *reinterpret_cast<const bf16x8*>(sA[cur] + aoff[i]);
#pragma unroll
    for (int j = 0; j < 4; ++j)
      bfr[j] = *reinterpret_cast<const bf16x8*>(sB[cur] + boff[j]);
    const int nxt = k0 + 32;
    if (nxt < K) stage(cur ^ 1, nxt);
#pragma unroll
    for (int i = 0; i < 8; ++i)
#pragma unroll
      for (int j = 0; j < 4; ++j)
        acc[i][j] = __builtin_amdgcn_mfma_f32_16x16x32_bf16(bfr[j], af[i], acc[i][j], 0, 0, 0);
    __syncthreads();                      // drains next-stage vmcnt + WAR
    cur ^= 1;
  }
  // C^T fragments: m = mbase + i*16; n = nbase + j*16 + e (quad along N)
  const int mbase = m0 + (wr << 7) + lr;
  const int nbase = n0 + (wc << 6) + (lk << 2);
#pragma unroll
  for (int i = 0; i < 8; ++i)
#pragma unroll
    for (int j = 0; j < 4; ++j) {
      const int m = mbase + (i << 4);
      const int n = nbase + (j << 4);
      const size_t off = (size_t)m * N + n;
      f32x4 v = acc[i][j];
      if (EPI == 0) {
        *reinterpret_cast<f32x4*>((float*)Cout + off) = v;
      } else {
        f32x4 o;
#pragma unroll
        for (int e = 0; e < 4; ++e) {
          const float ex = __expf(v[e] * (2.f / 15.f));
          o[e] = 15.f - 30.f / (ex + 1.f);
        }
        *reinterpret_cast<f32x4*>((float*)Cout + off) = o;
      }
    }
}

// ----------------------- gemm512: 128x128 / 8 waves ------------------------
// (R10 structure; chunk-rotation swizzle, conflicts measured 0)

template <int EPI>
__global__ __launch_bounds__(512)
void gemm512(const unsigned short* __restrict__ A,
             const unsigned short* __restrict__ Bw,
             void* __restrict__ Cout,
             int M, int N, int K, int kchunk) {
  __shared__ unsigned short sA[2][128 * 32];
  __shared__ unsigned short sB[2][128 * 32];
  const int tid = threadIdx.x;

  int flat = blockIdx.x + gridDim.x * blockIdx.y;
  const int nwg = gridDim.x * gridDim.y;
  if ((nwg & 7) == 0) flat = (flat & 7) * (nwg >> 3) + (flat >> 3);
  const int m0 = (flat % gridDim.x) << 7;
  const int n0 = (flat / gridDim.x) << 7;
  const int k_begin = blockIdx.z * kchunk;
  int k_end = k_begin + kchunk; if (k_end > K) k_end = K;

  const int wid = tid >> 6, lane = tid & 63;
  const int wr = wid >> 2, wc = wid & 3;           // 2 x 4 wave grid
  const int lr = lane & 15, lk = lane >> 4;

  const int row0 = tid >> 2;
  const int srcch = (((tid & 3) - (tid >> 3)) & 3) << 3;
  const unsigned short* gA = A + (size_t)(m0 + row0) * K + srcch;
  const unsigned short* gB = Bw + (size_t)(n0 + row0) * K + srcch;

  auto stage = [&](int buf, int k0) {
    gload16(gA + k0, sA[buf] + tid * 8);
    gload16(gB + k0, sB[buf] + tid * 8);
  };

  int aoff[4], boff[2];
#pragma unroll
  for (int i = 0; i < 4; ++i) {
    const int r = (wr << 6) + (i << 4) + lr;
    aoff[i] = r * 32 + (((lk + (r >> 1)) & 3) << 3);
  }
#pragma unroll
  for (int j = 0; j < 2; ++j) {
    const int r = (wc << 5) + (j << 4) + lr;
    boff[j] = r * 32 + (((lk + (r >> 1)) & 3) << 3);
  }

  f32x4 acc[4][2] = {};
  int cur = 0;
  stage(0, k_begin);
  __syncthreads();
  for (int k0 = k_begin; k0 < k_end; k0 += 32) {
    bf16x8 af[4], bfr[2];
#pragma unroll
    for (int i = 0; i < 4; ++i)
      af[i] = *reinterpret_cast<const bf16x8*>(sA[cur] + aoff[i]);
#pragma unroll
    for (int j = 0; j < 2; ++j)
      bfr[j] = *reinterpret_cast<const bf16x8*>(sB[cur] + boff[j]);
    const int nxt = k0 + 32;
    if (nxt < k_end) stage(cur ^ 1, nxt);
#pragma unroll
    for (int i = 0; i < 4; ++i)
#pragma unroll
      for (int j = 0; j < 2; ++j)
        acc[i][j] = __builtin_amdgcn_mfma_f32_16x16x32_bf16(bfr[j], af[i], acc[i][j], 0, 0, 0);
    __syncthreads();
    cur ^= 1;
  }
  const int mbase = m0 + (wr << 6) + lr;
  const int nbase = n0 + (wc << 5) + (lk << 2);
  float* outF = (float*)Cout + (size_t)blockIdx.z * M * N;
#pragma unroll
  for (int i = 0; i < 4; ++i)
#pragma unroll
    for (int j = 0; j < 2; ++j) {
      const int m = mbase + (i << 4);
      const int n = nbase + (j << 4);
      const size_t off = (size_t)m * N + n;
      f32x4 v = acc[i][j];
      if (EPI == 0) {
        *reinterpret_cast<f32x4*>(outF + off) = v;
      } else if (EPI == 2) {
        ushort4 u;
        float r0 = v[0] > 0.f ? v[0] : 0.f;
        float r1 = v[1] > 0.f ? v[1] : 0.f;
        float r2 = v[2] > 0.f ? v[2] : 0.f;
        float r3 = v[3] > 0.f ? v[3] : 0.f;
        u.x = f2bf(r0 * r0); u.y = f2bf(r1 * r1);
        u.z = f2bf(r2 * r2); u.w = f2bf(r3 * r3);
        *reinterpret_cast<ushort4*>((unsigned short*)Cout + off) = u;
      } else {
        f32x4 o;
#pragma unroll
        for (int e = 0; e < 4; ++e) {
          const float ex = __expf(v[e] * (2.f / 15.f));
          o[e] = 15.f - 30.f / (ex + 1.f);
        }
        *reinterpret_cast<f32x4*>((float*)Cout + off) = o;
      }
    }
}

// ----------------- legacy 256-thread GEMM (Wo only: 128x64) ----------------

template <int EPI, int NJ>
__global__ __launch_bounds__(256)
void gemm_bf16(const unsigned short* __restrict__ A,
               const unsigned short* __restrict__ Bw,
               const float* __restrict__ Cin, void* __restrict__ Cout,
               int M, int N, int K, int kchunk) {
  constexpr int BN = NJ * 32;
  __shared__ unsigned short sA[2][128 * 32];
  __shared__ unsigned short sB[2][BN * 32];
  const int tid = threadIdx.x;

  int flat = blockIdx.x + gridDim.x * blockIdx.y;
  const int nwg = gridDim.x * gridDim.y;
  if ((nwg & 7) == 0) flat = (flat & 7) * (nwg >> 3) + (flat >> 3);
  const int m0 = (flat % gridDim.x) << 7;
  const int n0 = (flat / gridDim.x) * BN;
  const int k_begin = blockIdx.z * kchunk;
  int k_end = k_begin + kchunk; if (k_end > K) k_end = K;

  const int wid = tid >> 6, lane = tid & 63;
  const int wr = wid >> 1, wc = wid & 1;
  const int lr = lane & 15, lk = lane >> 4;

  const int row0 = tid >> 2, ch0 = (tid & 3) << 3;
  const unsigned short* gA0 = A + (size_t)(m0 + row0) * K + ch0;
  const unsigned short* gA1 = gA0 + (size_t)64 * K;
  const unsigned short* gB0 = Bw + (size_t)(n0 + row0) * K + ch0;
  const int lofs = wid << 9;

  auto stage = [&](int buf, int k0) {
    gload16(gA0 + k0, sA[buf] + lofs);
    gload16(gA1 + k0, sA[buf] + lofs + 2048);
    gload16(gB0 + k0, sB[buf] + lofs);
  };

  f32x4 acc[4][NJ] = {};
  int cur = 0;
  stage(0, k_begin);
  __syncthreads();
  for (int k0 = k_begin; k0 < k_end; k0 += 32) {
    bf16x8 af[4], bfr[NJ];
#pragma unroll
    for (int i = 0; i < 4; ++i)
      af[i] = *reinterpret_cast<const bf16x8*>(sA[cur] + ((wr << 6) + (i << 4) + lr) * 32 + (lk << 3));
#pragma unroll
    for (int j = 0; j < NJ; ++j)
      bfr[j] = *reinterpret_cast<const bf16x8*>(sB[cur] + (wc * (BN / 2) + (j << 4) + lr) * 32 + (lk << 3));
    const int nxt = k0 + 32;
    if (nxt < k_end) stage(cur ^ 1, nxt);
#pragma unroll
    for (int i = 0; i < 4; ++i)
#pragma unroll
      for (int j = 0; j < NJ; ++j)
        acc[i][j] = __builtin_amdgcn_mfma_f32_16x16x32_bf16(bfr[j], af[i], acc[i][j], 0, 0, 0);
    __syncthreads();
    cur ^= 1;
  }
  const int mbase = m0 + (wr << 6) + lr;
  const int nbase = n0 + wc * (BN / 2) + (lk << 2);
  float* outF = (float*)Cout + (size_t)blockIdx.z * M * N;
#pragma unroll
  for (int i = 0; i < 4; ++i)
#pragma unroll
    for (int j = 0; j < NJ; ++j) {
      const int m = mbase + (i << 4);
      const int n = nbase + (j << 4);
      const size_t off = (size_t)m * N + n;
      *reinterpret_cast<f32x4*>(outF + off) = acc[i][j];
    }
  (void)Cin;
}

// ------------------------------- launcher ----------------------------------

extern "C" void kernel_launch(void* const* d_in, const int* in_sizes, int n_in,
                              void* d_out, int out_size, void* d_ws, size_t ws_size,
                              hipStream_t stream) {
  (void)in_sizes; (void)n_in; (void)out_size; (void)ws_size;
  const int*   ids  = (const int*)  d_in[0];
  const float* wte  = (const float*)d_in[1];
  const float* Wq   = (const float*)d_in[2];
  const float* Wk   = (const float*)d_in[3];
  const float* Wv   = (const float*)d_in[4];
  const float* Wo   = (const float*)d_in[5];
  const float* Wfc  = (const float*)d_in[6];
  const float* Wmp  = (const float*)d_in[7];
  const float* VeT  = (const float*)d_in[8];
  const float* VeG  = (const float*)d_in[9];
  const float* LmW  = (const float*)d_in[10];
  const float* ResC = (const float*)d_in[11];
  const float* X0C  = (const float*)d_in[12];
  const float* SmW  = (const float*)d_in[13];
  const float* SmL  = (const float*)d_in[14];

  char* p = (char*)d_ws;
  auto alloc = [&](size_t bytes) -> char* {
    char* r = p; p += (bytes + 255) & ~(size_t)255; return r;
  };
  float* x  = (float*)alloc((size_t)2048 * 1024 * 4);
  float* x0 = (float*)alloc((size_t)2048 * 1024 * 4);
  unsigned short* xn = (unsigned short*)alloc((size_t)2048 * 1024 * 2);
  unsigned short* hidden = (unsigned short*)alloc((size_t)2048 * 4096 * 2);
  float* qkvp = (float*)alloc((size_t)2 * 2048 * 1536 * 4);   // qkv split-K partials
  float* wop  = (float*)alloc((size_t)2 * 2048 * 1024 * 4);   // Wo split-K partials
  float* mpp  = (float*)alloc((size_t)4 * 2048 * 1024 * 4);   // MP split-K partials
  unsigned short* qbuf = (unsigned short*)alloc((size_t)2048 * 1024 * 2);
  unsigned short* kbuf = (unsigned short*)alloc((size_t)2048 * 256 * 2);
  unsigned short* vbuf = (unsigned short*)alloc((size_t)2048 * 256 * 2);
  unsigned short* vtb  = (unsigned short*)alloc((size_t)2048 * 256 * 2);
  unsigned short* ybuf = (unsigned short*)alloc((size_t)2048 * 1024 * 2);
  float* cost = (float*)alloc((size_t)1024 * 32 * 4);
  float* sint = (float*)alloc((size_t)1024 * 32 * 4);
  unsigned short* wqkv = (unsigned short*)alloc((size_t)6 * 1536 * 1024 * 2);
  unsigned short* wo   = (unsigned short*)alloc((size_t)6 * 1024 * 1024 * 2);
  unsigned short* wfc  = (unsigned short*)alloc((size_t)6 * 4096 * 1024 * 2);
  unsigned short* wmp  = (unsigned short*)alloc((size_t)6 * 1024 * 4096 * 2);
  unsigned short* wlm  = (unsigned short*)alloc((size_t)32000 * 1024 * 2);

  prep_weights_kernel<<<48256, 256, 0, stream>>>(Wq, Wk, Wv, Wo, Wfc, Wmp, LmW,
                                                 wqkv, wo, wfc, wmp, wlm);
  rope_tab_kernel<<<128, 256, 0, stream>>>(cost, sint);
  embed_kernel<<<512, 256, 0, stream>>>(ids, wte, SmW, SmL, ResC, X0C, x, x0, xn);

  static const int WIN[6] = {256, 1024, 256, 1024, 256, 1024};
  for (int l = 0; l < 6; ++l) {
    if (l > 0)
      rmsnorm_kernel<<<512, 256, 0, stream>>>(x, x0, mpp, 4, ResC, X0C, l, 1, xn);
    // QKV: split-K x2 -> two partial planes (summed inside qkv_post)
    gemm512<0><<<dim3(16, 12, 2), 512, 0, stream>>>(xn, wqkv + (size_t)l * 1536 * 1024,
                                                    qkvp, 2048, 1536, 1024, 512);
    const float* vtab = nullptr; const float* vgw = nullptr;
    if (l == 1 || l == 3 || l == 5) {
      const int vi = (l - 1) / 2;
      vtab = VeT + (size_t)vi * 32000 * 256;
      vgw  = VeG + vi * 48;
    }
    qkv_post_kernel<<<512, 256, 0, stream>>>(qkvp, qkvp + (size_t)2048 * 1536, xn, ids,
                                             vtab, vgw, cost, sint, qbuf, kbuf, vbuf);
    vtrans_kernel<<<dim3(16, 8), 256, 0, stream>>>(vbuf, vtb);
    attn_kernel<<<dim3(64, 16, 2), 64, 0, stream>>>(qbuf, kbuf, vtb, ybuf, WIN[l]);
    // Wo: split-K x2 -> partials (reduced + added to x by next rmsnorm)
    gemm_bf16<0, 2><<<dim3(16, 16, 2), 256, 0, stream>>>(ybuf, wo + (size_t)l * 1024 * 1024,
                                                         nullptr, wop, 2048, 1024, 1024, 512);
    rmsnorm_kernel<<<512, 256, 0, stream>>>(x, x0, wop, 2, ResC, X0C, l, 0, xn);
    gemm512<2><<<dim3(16, 32), 512, 0, stream>>>(xn, wfc + (size_t)l * 4096 * 1024,
                                                 hidden, 2048, 4096, 1024, 1024);
    // MP: split-K x4 (K=4096) -> partials (reduced by next layer's rmsnorm)
    gemm512<0><<<dim3(16, 8, 4), 512, 0, stream>>>(hidden, wmp + (size_t)l * 1024 * 4096,
                                                   mpp, 2048, 1024, 4096, 1024);
  }
  rmsnorm_kernel<<<512, 256, 0, stream>>>(x, x0, mpp, 4, ResC, X0C, 0, 0, xn);
  // LM head: 256x256 2-phase tile, grid 8 x 125 = 1000 blocks (2 blocks/CU)
  gemm256b<3><<<dim3(8, 125), 512, 0, stream>>>(xn, wlm, (float*)d_out,
                                                2048, 32000, 1024);
}